// Round 7
// baseline (6647.787 us; speedup 1.0000x reference)
//
#include <hip/hip_runtime.h>
#include <hip/hip_bf16.h>
#include <math.h>

#define DIMD 512
#define SEQL 4096
#define KU 1024
#define KF 1536
#define NJ 8192
#define KC 384          // OpenBLAS sgemm K-blocking (matched in round 5)

#define BM 64
#define BK 32
#define PA 33
#define PW 68

#define GAP_T 1e-3f

// ws layout (bytes)
#define WS_R    0
#define WS_C4   4096
#define WS_BC   (4096 + 65536)
#define WS_E    262144
#define WS_FLAG (262144 + (size_t)SEQL * NJ * 2)
#define WS_NEEDED (WS_FLAG + (size_t)SEQL * DIMD)

typedef __attribute__((ext_vector_type(8))) short bf16x8;
typedef __attribute__((ext_vector_type(4))) float f32x4;

__device__ __forceinline__ ushort f2bf(float f) {
    __hip_bfloat16 h = __float2bfloat16(f);
    return *reinterpret_cast<ushort*>(&h);
}
__device__ __forceinline__ float bf2f(ushort v) {
    unsigned int b = ((unsigned int)v) << 16;
    return __uint_as_float(b);
}

// ---- f32 R with the exact chunked fma chain (k-ascending, KC blocks) ----
__device__ __forceinline__ float chainR(
    const float* __restrict__ h, const float* __restrict__ us, const float* __restrict__ ue,
    const float* __restrict__ Wr, const float* __restrict__ br, int o)
{
    float accT = 0.f;
    for (int k0 = 0; k0 < 2560; k0 += KC) {
        int ke = (k0 + KC < 2560) ? k0 + KC : 2560;
        float accC = 0.f;
        for (int k = k0; k < ke; ++k) {
            float xv = (k < 1536) ? h[k] : (k < 2048) ? us[k - 1536] : ue[k - 2048];
            accC = fmaf(xv, Wr[(size_t)o * 2560 + k], accC);
        }
        accT = __fadd_rn(accT, accC);
    }
    return __fadd_rn(accT, br[o]);
}

__global__ __launch_bounds__(256) void k_R32(
    const float* __restrict__ h, const float* __restrict__ us, const float* __restrict__ ue,
    const float* __restrict__ Wr, const float* __restrict__ br, float* __restrict__ Rout)
{
    int o = blockIdx.x * 256 + threadIdx.x;
    Rout[o] = chainR(h, us, ue, Wr, br, o);
}

// ---- chunk-4 exact chain: c4[mat*NJ+j] = f32 chain over k in [1152,1536) ----
__global__ __launch_bounds__(256) void k_c4(
    const float* __restrict__ R32, const float* __restrict__ Wnn,
    const float* __restrict__ Wno, float* __restrict__ c4)
{
    int idx = blockIdx.x * 256 + threadIdx.x;    // 0..16383
    int mat = idx >> 13, j = idx & 8191;
    const float* W = mat ? Wno : Wnn;
    float c = 0.f;
    for (int k = 1152; k < 1536; ++k)
        c = fmaf(R32[k - KU], W[(size_t)j * KF + k], c);
    c4[idx] = c;
}

// ---- approx combined bias for the gate: Bc[mat*NJ+j] = R.W[1024:1536) + b (f64 fold) ----
__global__ __launch_bounds__(256) void k_bc(
    const float* __restrict__ R32, const float* __restrict__ Wnn, const float* __restrict__ Wno,
    const float* __restrict__ bnn, const float* __restrict__ bno, float* __restrict__ Bc)
{
    int idx = blockIdx.x * 256 + threadIdx.x;    // 0..16383
    int mat = idx >> 13, j = idx & 8191;
    const float* W = mat ? Wno : Wnn;
    const float* b = mat ? bno : bnn;
    double acc = 0.0;
    for (int k = 1024; k < 1536; ++k)
        acc += (double)R32[k - KU] * (double)W[(size_t)j * KF + k];
    Bc[idx] = (float)(acc + (double)b[j]);
}

// ---- E-path: e = x @ W_E^T + b_E via bf16 MFMA, bf16 out to ws ----
#define EB 128
#define EPAD 40
__global__ __launch_bounds__(256) void k_e(
    const float* __restrict__ u, const float* __restrict__ R32,
    const float* __restrict__ WE, const float* __restrict__ bE,
    __hip_bfloat16* __restrict__ eout)
{
    __shared__ ushort Asb[EB][EPAD];
    __shared__ ushort Bsb[EB][EPAD];
    const int tid = threadIdx.x;
    const int w = tid >> 6, l = tid & 63;
    const int wm = w >> 1, wn = w & 1;
    const int sBase = blockIdx.y * EB;
    const int jBase = blockIdx.x * EB;

    f32x4 acc[4][4] = {};

    for (int kt = 0; kt < KF; kt += BK) {
        __syncthreads();
        #pragma unroll
        for (int it = 0; it < 4; ++it) {
            int idx = tid + it * 256;
            int row = idx >> 3, c4o = (idx & 7) << 2;
            float4 v;
            if (kt < KU) v = *(const float4*)&u[(size_t)(sBase + row) * KU + kt + c4o];
            else         v = *(const float4*)&R32[kt - KU + c4o];
            ushort4 o;
            o.x = f2bf(v.x); o.y = f2bf(v.y); o.z = f2bf(v.z); o.w = f2bf(v.w);
            *(ushort4*)&Asb[row][c4o] = o;
        }
        #pragma unroll
        for (int it = 0; it < 4; ++it) {
            int idx = tid + it * 256;
            int col = idx >> 3, c4o = (idx & 7) << 2;
            float4 v = *(const float4*)&WE[(size_t)(jBase + col) * KF + kt + c4o];
            ushort4 o;
            o.x = f2bf(v.x); o.y = f2bf(v.y); o.z = f2bf(v.z); o.w = f2bf(v.w);
            *(ushort4*)&Bsb[col][c4o] = o;
        }
        __syncthreads();
        const int kq = (l >> 4) << 3;
        bf16x8 af[4], bff[4];
        #pragma unroll
        for (int i = 0; i < 4; ++i)
            af[i] = *(const bf16x8*)&Asb[wm * 64 + i * 16 + (l & 15)][kq];
        #pragma unroll
        for (int n = 0; n < 4; ++n)
            bff[n] = *(const bf16x8*)&Bsb[wn * 64 + n * 16 + (l & 15)][kq];
        #pragma unroll
        for (int i = 0; i < 4; ++i)
            #pragma unroll
            for (int n = 0; n < 4; ++n)
                acc[i][n] = __builtin_amdgcn_mfma_f32_16x16x32_bf16(af[i], bff[n], acc[i][n], 0, 0, 0);
    }
    #pragma unroll
    for (int i = 0; i < 4; ++i) {
        int row = sBase + wm * 64 + i * 16 + ((l >> 4) << 2);
        #pragma unroll
        for (int n = 0; n < 4; ++n) {
            int col = jBase + wn * 64 + n * 16 + (l & 15);
            float bb = bE[col];
            #pragma unroll
            for (int r = 0; r < 4; ++r)
                eout[(size_t)(row + r) * NJ + col] = __float2bfloat16(acc[i][n][r] + bb);
        }
    }
}

// ---- m-path: split-bf16 MFMA (u1w1+u1w2+u2w1) for both mats + fused gate ----
#define MP 40
union MSm {
    struct {
        ushort u1[128][MP], u2[128][MP];
        ushort w1[2][64][MP], w2[2][64][MP];
    } st;
    struct { float m[128][64]; } ep;
};

__global__ __launch_bounds__(256, 2) void k_m(
    const float* __restrict__ u, const float* __restrict__ noise,
    const float* __restrict__ Wnn, const float* __restrict__ Wno,
    const float* __restrict__ Bc, const __hip_bfloat16* __restrict__ ews,
    unsigned char* __restrict__ flags, float* __restrict__ out)
{
    __shared__ MSm sm;
    const int tid = threadIdx.x;
    const int w = tid >> 6, l = tid & 63;
    const int wm = w >> 1, wn = w & 1;
    const int lr = l & 15;
    const int sBase = blockIdx.y * 128;
    const int jBase = blockIdx.x * 64;
    const int dBase = jBase >> 4;

    f32x4 acc1[4][2] = {}; f32x4 acc2[4][2] = {};

    for (int kt = 0; kt < KU; kt += BK) {
        __syncthreads();
        #pragma unroll
        for (int it = 0; it < 4; ++it) {
            int idx = tid + it * 256;
            int row = idx >> 3, c4o = (idx & 7) << 2;
            float4 v = *(const float4*)&u[(size_t)(sBase + row) * KU + kt + c4o];
            ushort4 hA, hB;
            hA.x = f2bf(v.x); hB.x = f2bf(v.x - bf2f(hA.x));
            hA.y = f2bf(v.y); hB.y = f2bf(v.y - bf2f(hA.y));
            hA.z = f2bf(v.z); hB.z = f2bf(v.z - bf2f(hA.z));
            hA.w = f2bf(v.w); hB.w = f2bf(v.w - bf2f(hA.w));
            *(ushort4*)&sm.st.u1[row][c4o] = hA;
            *(ushort4*)&sm.st.u2[row][c4o] = hB;
        }
        #pragma unroll
        for (int it = 0; it < 4; ++it) {
            int idx = tid + it * 256;
            int mat = idx >> 9, col = (idx >> 3) & 63, c4o = (idx & 7) << 2;
            const float* W = mat ? Wno : Wnn;
            float4 v = *(const float4*)&W[(size_t)(jBase + col) * KF + kt + c4o];
            ushort4 hA, hB;
            hA.x = f2bf(v.x); hB.x = f2bf(v.x - bf2f(hA.x));
            hA.y = f2bf(v.y); hB.y = f2bf(v.y - bf2f(hA.y));
            hA.z = f2bf(v.z); hB.z = f2bf(v.z - bf2f(hA.z));
            hA.w = f2bf(v.w); hB.w = f2bf(v.w - bf2f(hA.w));
            *(ushort4*)&sm.st.w1[mat][col][c4o] = hA;
            *(ushort4*)&sm.st.w2[mat][col][c4o] = hB;
        }
        __syncthreads();
        const int kq = (l >> 4) << 3;
        bf16x8 a1[4], a2[4], p1[2][2], p2[2][2];
        #pragma unroll
        for (int i = 0; i < 4; ++i) {
            a1[i] = *(const bf16x8*)&sm.st.u1[wm * 64 + i * 16 + lr][kq];
            a2[i] = *(const bf16x8*)&sm.st.u2[wm * 64 + i * 16 + lr][kq];
        }
        #pragma unroll
        for (int mt = 0; mt < 2; ++mt)
            #pragma unroll
            for (int n = 0; n < 2; ++n) {
                p1[mt][n] = *(const bf16x8*)&sm.st.w1[mt][wn * 32 + n * 16 + lr][kq];
                p2[mt][n] = *(const bf16x8*)&sm.st.w2[mt][wn * 32 + n * 16 + lr][kq];
            }
        #pragma unroll
        for (int i = 0; i < 4; ++i)
            #pragma unroll
            for (int n = 0; n < 2; ++n) {
                acc1[i][n] = __builtin_amdgcn_mfma_f32_16x16x32_bf16(a1[i], p1[0][n], acc1[i][n], 0, 0, 0);
                acc1[i][n] = __builtin_amdgcn_mfma_f32_16x16x32_bf16(a1[i], p2[0][n], acc1[i][n], 0, 0, 0);
                acc1[i][n] = __builtin_amdgcn_mfma_f32_16x16x32_bf16(a2[i], p1[0][n], acc1[i][n], 0, 0, 0);
                acc2[i][n] = __builtin_amdgcn_mfma_f32_16x16x32_bf16(a1[i], p1[1][n], acc2[i][n], 0, 0, 0);
                acc2[i][n] = __builtin_amdgcn_mfma_f32_16x16x32_bf16(a1[i], p2[1][n], acc2[i][n], 0, 0, 0);
                acc2[i][n] = __builtin_amdgcn_mfma_f32_16x16x32_bf16(a2[i], p1[1][n], acc2[i][n], 0, 0, 0);
            }
    }

    __syncthreads();
    // fold biases + noise, write m tile to LDS
    float bc1[2], bc2[2];
    #pragma unroll
    for (int n = 0; n < 2; ++n) {
        int col = jBase + wn * 32 + n * 16 + lr;
        bc1[n] = Bc[col];
        bc2[n] = Bc[NJ + col];
    }
    #pragma unroll
    for (int i = 0; i < 4; ++i)
        #pragma unroll
        for (int n = 0; n < 2; ++n) {
            int colL = wn * 32 + n * 16 + lr;
            #pragma unroll
            for (int r = 0; r < 4; ++r) {
                int rowL = wm * 64 + i * 16 + ((l >> 4) << 2) + r;
                float m1 = acc1[i][n][r] + bc1[n];
                float m2 = acc2[i][n][r] + bc2[n];
                float nz = noise[(size_t)(sBase + rowL) * NJ + jBase + colL];
                sm.ep.m[rowL][colL] = fmaf(m2, nz, m1);
            }
        }
    __syncthreads();

    // gate: 512 (s,d) sites per block, 2 per thread
    for (int site = tid; site < 512; site += 256) {
        int srow = site >> 2, dl = site & 3;
        const __hip_bfloat16* ep = &ews[(size_t)(sBase + srow) * NJ + jBase + dl * 16];
        float v1 = -INFINITY, v2 = -INFINITY, v3 = -INFINITY;
        float ev1 = 0.f, ev2 = 0.f;
        #pragma unroll
        for (int e = 0; e < 16; ++e) {
            float m = sm.ep.m[srow][dl * 16 + e];
            float ev = bf2f(*reinterpret_cast<const ushort*>(&ep[e]));
            if (m > v1)      { v3 = v2; v2 = v1; ev2 = ev1; v1 = m; ev1 = ev; }
            else if (m > v2) { v3 = v2; v2 = m; ev2 = ev; }
            else if (m > v3) { v3 = m; }
        }
        int gidx = (sBase + srow) * DIMD + dBase + dl;
        bool flg = (v2 - v3 < GAP_T) || (fabsf(v1) < GAP_T) || (fabsf(v2) < GAP_T);
        flags[gidx] = flg ? (unsigned char)1 : (unsigned char)0;
        double x1 = (double)v1, x2 = (double)v2;
        double vmax = fmax(x1, x2);
        double g1 = exp(x1 - vmax), g2 = exp(x2 - vmax);
        double num = g1 * (double)ev1 + g2 * (double)ev2;
        out[gidx] = (float)(num / (g1 + g2) * 0.0625);
    }
}

// ---- repair: exact round-5 chain arithmetic for flagged sites ----
__global__ __launch_bounds__(256) void k_repair(
    const float* __restrict__ u, const float* __restrict__ noise,
    const float* __restrict__ Wnn, const float* __restrict__ Wno,
    const float* __restrict__ bnn, const float* __restrict__ bno,
    const float* __restrict__ R32, const float* __restrict__ c4ws,
    const __hip_bfloat16* __restrict__ ews,
    const unsigned char* __restrict__ flags, float* __restrict__ out)
{
    int t0 = (blockIdx.x * 256 + threadIdx.x) * 8;
    for (int si = t0; si < t0 + 8; ++si) {
        if (!flags[si]) continue;
        int s = si >> 9, d = si & 511;
        int jb = d * 16;
        float v1 = -INFINITY, v2 = -INFINITY;
        double ev1 = 0.0, ev2 = 0.0, sumE = 0.0;
        for (int e = 0; e < 16; ++e) {
            int j = jb + e;
            const float* W1 = &Wnn[(size_t)j * KF];
            const float* W2 = &Wno[(size_t)j * KF];
            float tA = 0.f, tB = 0.f;
            for (int c = 0; c < 3; ++c) {
                float cA = 0.f, cB = 0.f;
                int k0 = c * KC, k1 = k0 + KC;
                for (int k = k0; k < k1; ++k) {
                    float a = (k < KU) ? u[(size_t)s * KU + k] : R32[k - KU];
                    cA = fmaf(a, W1[k], cA);
                    cB = fmaf(a, W2[k], cB);
                }
                tA = __fadd_rn(tA, cA);
                tB = __fadd_rn(tB, cB);
            }
            tA = __fadd_rn(tA, c4ws[j]);
            tB = __fadd_rn(tB, c4ws[NJ + j]);
            float h1 = __fadd_rn(tA, bnn[j]);
            float h2 = __fadd_rn(tB, bno[j]);
            float nz = noise[(size_t)s * NJ + j];
            float m = __fadd_rn(h1, __fmul_rn(h2, nz));
            double ev = (double)bf2f(*reinterpret_cast<const ushort*>(&ews[(size_t)s * NJ + j]));
            sumE += ev;
            if (m > v1)      { v2 = v1; ev2 = ev1; v1 = m; ev1 = ev; }
            else if (m > v2) { v2 = m; ev2 = ev; }
        }
        double x1 = (v1 == 0.0f) ? -100000.0 : (double)v1;
        double x2 = (v2 == 0.0f) ? -100000.0 : (double)v2;
        double vmax = fmax(fmax(x1, x2), -100000.0);
        double g1 = exp(x1 - vmax), g2 = exp(x2 - vmax), gz = exp(-100000.0 - vmax);
        double den = g1 + g2 + 14.0 * gz;
        double num = g1 * ev1 + g2 * ev2 + gz * (sumE - ev1 - ev2);
        out[si] = (float)(num / den * 0.0625);
    }
}

// ---- fallback: proven round-5 ws-free kernel (bit-identical arithmetic) ----
__global__ __launch_bounds__(256) void k_base(
    const float* __restrict__ u, const float* __restrict__ noise,
    const float* __restrict__ Wnn, const float* __restrict__ Wno, const float* __restrict__ WE,
    const float* __restrict__ bnn, const float* __restrict__ bno, const float* __restrict__ bE,
    const float* __restrict__ h, const float* __restrict__ us, const float* __restrict__ ue,
    const float* __restrict__ Wr, const float* __restrict__ br,
    float* __restrict__ out)
{
    __shared__ __align__(16) float As[BM][PA];
    __shared__ __align__(16) float Ws[3][BK][PW];
    __shared__ float Rsh[512];

    const int tid = threadIdx.x;
    const int sr = tid >> 2, dl = tid & 3;
    const int jBase = blockIdx.x * 64;
    const int sBase = blockIdx.y * BM;
    const int myCol = dl * 16;

    for (int o = tid; o < 512; o += 256) Rsh[o] = chainR(h, us, ue, Wr, br, o);

    float t1[16] = {}, c1[16] = {}, t2[16] = {}, c2[16] = {}, tE[16] = {}, cE[16] = {};

    for (int kt = 0; kt < KF; kt += BK) {
        __syncthreads();
        if (kt < KU) {
            for (int idx = tid; idx < BM * BK; idx += 256) {
                int r = idx >> 5, c = idx & 31;
                As[r][c] = u[(size_t)(sBase + r) * KU + kt + c];
            }
        }
        for (int idx = tid; idx < 64 * BK; idx += 256) {
            int col = idx >> 5, kk = idx & 31;
            size_t off = (size_t)(jBase + col) * KF + kt + kk;
            Ws[0][kk][col] = Wnn[off];
            Ws[1][kk][col] = Wno[off];
            Ws[2][kk][col] = WE[off];
        }
        __syncthreads();
        const bool uReg = (kt < KU);
        for (int kk = 0; kk < BK; ++kk) {
            float a = uReg ? As[sr][kk] : Rsh[kt + kk - KU];
            #pragma unroll
            for (int q = 0; q < 4; ++q) {
                float4 w0 = *(const float4*)&Ws[0][kk][myCol + 4 * q];
                float4 w1 = *(const float4*)&Ws[1][kk][myCol + 4 * q];
                float4 w2 = *(const float4*)&Ws[2][kk][myCol + 4 * q];
                c1[4*q+0] = fmaf(a, w0.x, c1[4*q+0]);
                c1[4*q+1] = fmaf(a, w0.y, c1[4*q+1]);
                c1[4*q+2] = fmaf(a, w0.z, c1[4*q+2]);
                c1[4*q+3] = fmaf(a, w0.w, c1[4*q+3]);
                c2[4*q+0] = fmaf(a, w1.x, c2[4*q+0]);
                c2[4*q+1] = fmaf(a, w1.y, c2[4*q+1]);
                c2[4*q+2] = fmaf(a, w1.z, c2[4*q+2]);
                c2[4*q+3] = fmaf(a, w1.w, c2[4*q+3]);
                cE[4*q+0] = fmaf(a, w2.x, cE[4*q+0]);
                cE[4*q+1] = fmaf(a, w2.y, cE[4*q+1]);
                cE[4*q+2] = fmaf(a, w2.z, cE[4*q+2]);
                cE[4*q+3] = fmaf(a, w2.w, cE[4*q+3]);
            }
        }
        if (((kt + BK) % KC) == 0 || (kt + BK) == KF) {
            #pragma unroll
            for (int e = 0; e < 16; ++e) {
                t1[e] = __fadd_rn(t1[e], c1[e]); c1[e] = 0.f;
                t2[e] = __fadd_rn(t2[e], c2[e]); c2[e] = 0.f;
                tE[e] = __fadd_rn(tE[e], cE[e]); cE[e] = 0.f;
            }
        }
    }

    const int s = sBase + sr;
    const int jb = jBase + myCol;
    float m32[16]; double evv[16];
    #pragma unroll
    for (int e = 0; e < 16; ++e) {
        float h1 = __fadd_rn(t1[e], bnn[jb + e]);
        float h2 = __fadd_rn(t2[e], bno[jb + e]);
        float nz = noise[(size_t)s * NJ + jb + e];
        m32[e] = __fadd_rn(h1, __fmul_rn(h2, nz));
        evv[e] = (double)__fadd_rn(tE[e], bE[jb + e]);
    }
    int i1 = 0; float v1 = m32[0];
    #pragma unroll
    for (int e = 1; e < 16; ++e) if (m32[e] > v1) { v1 = m32[e]; i1 = e; }
    int i2 = -1; float v2 = -INFINITY;
    #pragma unroll
    for (int e = 0; e < 16; ++e) if (e != i1 && m32[e] > v2) { v2 = m32[e]; i2 = e; }
    double e1 = 0.0, e2 = 0.0, sumE = 0.0;
    #pragma unroll
    for (int e = 0; e < 16; ++e) {
        e1 = (e == i1) ? evv[e] : e1;
        e2 = (e == i2) ? evv[e] : e2;
        sumE += evv[e];
    }
    double x1 = (v1 == 0.0f) ? -100000.0 : (double)v1;
    double x2 = (v2 == 0.0f) ? -100000.0 : (double)v2;
    double vmax = fmax(fmax(x1, x2), -100000.0);
    double g1 = exp(x1 - vmax), g2 = exp(x2 - vmax), gz = exp(-100000.0 - vmax);
    double den = g1 + g2 + 14.0 * gz;
    double num = g1 * e1 + g2 * e2 + gz * (sumE - e1 - e2);
    out[(size_t)s * DIMD + (jBase >> 4) + dl] = (float)(num / den * 0.0625);
}

extern "C" void kernel_launch(void* const* d_in, const int* in_sizes, int n_in,
                              void* d_out, int out_size, void* d_ws, size_t ws_size,
                              hipStream_t stream) {
    (void)in_sizes; (void)n_in; (void)out_size;
    const float* h     = (const float*)d_in[0];
    const float* us    = (const float*)d_in[1];
    const float* ue    = (const float*)d_in[2];
    const float* u     = (const float*)d_in[3];
    const float* noise = (const float*)d_in[4];
    const float* Wnn   = (const float*)d_in[5];
    const float* bnn   = (const float*)d_in[6];
    const float* Wno   = (const float*)d_in[7];
    const float* bno   = (const float*)d_in[8];
    const float* WE    = (const float*)d_in[9];
    const float* bE    = (const float*)d_in[10];
    const float* Wr    = (const float*)d_in[11];
    const float* br    = (const float*)d_in[12];
    float* out = (float*)d_out;

    if (ws_size >= WS_NEEDED) {
        float* Rws  = (float*)((char*)d_ws + WS_R);
        float* c4ws = (float*)((char*)d_ws + WS_C4);
        float* Bc   = (float*)((char*)d_ws + WS_BC);
        __hip_bfloat16* ews = (__hip_bfloat16*)((char*)d_ws + WS_E);
        unsigned char* flags = (unsigned char*)((char*)d_ws + WS_FLAG);

        hipLaunchKernelGGL(k_R32, dim3(2), dim3(256), 0, stream, h, us, ue, Wr, br, Rws);
        hipLaunchKernelGGL(k_c4, dim3(64), dim3(256), 0, stream, Rws, Wnn, Wno, c4ws);
        hipLaunchKernelGGL(k_bc, dim3(64), dim3(256), 0, stream, Rws, Wnn, Wno, bnn, bno, Bc);
        hipLaunchKernelGGL(k_e, dim3(NJ / EB, SEQL / EB), dim3(256), 0, stream,
                           u, Rws, WE, bE, ews);
        hipLaunchKernelGGL(k_m, dim3(NJ / 64, SEQL / 128), dim3(256), 0, stream,
                           u, noise, Wnn, Wno, Bc, ews, flags, out);
        hipLaunchKernelGGL(k_repair, dim3(SEQL * DIMD / (8 * 256)), dim3(256), 0, stream,
                           u, noise, Wnn, Wno, bnn, bno, Rws, c4ws, ews, flags, out);
    } else {
        hipLaunchKernelGGL(k_base, dim3(NJ / 64, SEQL / BM), dim3(256), 0, stream,
                           u, noise, Wnn, Wno, WE, bnn, bno, bE,
                           h, us, ue, Wr, br, out);
    }
}

// Round 8
// 1509.891 us; speedup vs baseline: 4.4028x; 4.4028x over previous
//
#include <hip/hip_runtime.h>
#include <hip/hip_bf16.h>
#include <math.h>

#define DIMD 512
#define SEQL 4096
#define KU 1024
#define KF 1536
#define NJ 8192
#define KC 384          // OpenBLAS sgemm K-blocking (matched in round 5)

#define BM 64
#define BK 32
#define PA 33
#define PW 68

#define GAP_T 1e-3f

// ---- ws layout (bytes) ----
#define WS_R    0u                      // 512 f32
#define WS_C4   4096u                   // 2*8192 f32 (exact chunk-4 chains)
#define WS_BC   69632u                  // 2*8192 f32 (approx combined bias)
#define WS_CNT  135168u                 // int counter
#define WS_WL   135424u                 // worklist, up to 2.1M ints
#define WS_UHI  8524032u                // 4096*1024 bf16 (u hi split)
#define WS_ULO  16912640u               // 4096*1024 bf16 (u lo split)
#define WS_WEB  25301248u               // 8192*1536 bf16 (W_E)
#define WS_E    50467072u               // 4096*8192 bf16 (e matrix)
#define WS_NEEDED 117575936u

typedef __attribute__((ext_vector_type(8))) short bf16x8;
typedef __attribute__((ext_vector_type(4))) float f32x4;

__device__ __forceinline__ ushort f2bf(float f) {
    __hip_bfloat16 h = __float2bfloat16(f);
    return *reinterpret_cast<ushort*>(&h);
}
__device__ __forceinline__ float bf2f(ushort v) {
    unsigned int b = ((unsigned int)v) << 16;
    return __uint_as_float(b);
}

// ---- f32 R with the exact chunked fma chain (k-ascending, KC blocks) ----
__device__ __forceinline__ float chainR(
    const float* __restrict__ h, const float* __restrict__ us, const float* __restrict__ ue,
    const float* __restrict__ Wr, const float* __restrict__ br, int o)
{
    float accT = 0.f;
    for (int k0 = 0; k0 < 2560; k0 += KC) {
        int ke = (k0 + KC < 2560) ? k0 + KC : 2560;
        float accC = 0.f;
        for (int k = k0; k < ke; ++k) {
            float xv = (k < 1536) ? h[k] : (k < 2048) ? us[k - 1536] : ue[k - 2048];
            accC = fmaf(xv, Wr[(size_t)o * 2560 + k], accC);
        }
        accT = __fadd_rn(accT, accC);
    }
    return __fadd_rn(accT, br[o]);
}

__global__ __launch_bounds__(256) void k_R32(
    const float* __restrict__ h, const float* __restrict__ us, const float* __restrict__ ue,
    const float* __restrict__ Wr, const float* __restrict__ br, float* __restrict__ Rout)
{
    int o = blockIdx.x * 256 + threadIdx.x;
    Rout[o] = chainR(h, us, ue, Wr, br, o);
}

// ---- prep: u -> bf16 hi/lo splits ----
__global__ __launch_bounds__(256) void k_prep_u(
    const float* __restrict__ u, ushort* __restrict__ uhi, ushort* __restrict__ ulo)
{
    size_t i4 = (size_t)(blockIdx.x * 256 + threadIdx.x) * 4;
    float4 v = *(const float4*)&u[i4];
    ushort4 a, b;
    a.x = f2bf(v.x); b.x = f2bf(v.x - bf2f(a.x));
    a.y = f2bf(v.y); b.y = f2bf(v.y - bf2f(a.y));
    a.z = f2bf(v.z); b.z = f2bf(v.z - bf2f(a.z));
    a.w = f2bf(v.w); b.w = f2bf(v.w - bf2f(a.w));
    *(ushort4*)&uhi[i4] = a;
    *(ushort4*)&ulo[i4] = b;
}

// ---- prep: W_E -> bf16 ----
__global__ __launch_bounds__(256) void k_prep_we(
    const float* __restrict__ WE, ushort* __restrict__ web)
{
    size_t i4 = (size_t)(blockIdx.x * 256 + threadIdx.x) * 4;
    float4 v = *(const float4*)&WE[i4];
    ushort4 a;
    a.x = f2bf(v.x); a.y = f2bf(v.y); a.z = f2bf(v.z); a.w = f2bf(v.w);
    *(ushort4*)&web[i4] = a;
}

// ---- chunk-4 exact chain: c4[mat*NJ+j] = f32 chain over k in [1152,1536) ----
__global__ __launch_bounds__(256) void k_c4(
    const float* __restrict__ R32, const float* __restrict__ Wnn,
    const float* __restrict__ Wno, float* __restrict__ c4)
{
    int idx = blockIdx.x * 256 + threadIdx.x;
    int mat = idx >> 13, j = idx & 8191;
    const float* W = mat ? Wno : Wnn;
    float c = 0.f;
    for (int k = 1152; k < 1536; ++k)
        c = fmaf(R32[k - KU], W[(size_t)j * KF + k], c);
    c4[idx] = c;
}

// ---- approx combined bias: Bc[mat*NJ+j] = R.W[1024:1536) + b (f64 fold) ----
__global__ __launch_bounds__(256) void k_bc(
    const float* __restrict__ R32, const float* __restrict__ Wnn, const float* __restrict__ Wno,
    const float* __restrict__ bnn, const float* __restrict__ bno, float* __restrict__ Bc)
{
    int idx = blockIdx.x * 256 + threadIdx.x;
    int mat = idx >> 13, j = idx & 8191;
    const float* W = mat ? Wno : Wnn;
    const float* b = mat ? bno : bnn;
    double acc = 0.0;
    for (int k = 1024; k < 1536; ++k)
        acc += (double)R32[k - KU] * (double)W[(size_t)j * KF + k];
    Bc[idx] = (float)(acc + (double)b[j]);
}

__global__ void k_zero(int* __restrict__ cnt) { *cnt = 0; }

// ---- E-path: e = x @ W_E^T + b_E via bf16 MFMA (precvt inputs), bf16 out ----
#define EB 128
#define EPAD 40
__global__ __launch_bounds__(256) void k_e(
    const ushort* __restrict__ uhi, const float* __restrict__ R32,
    const ushort* __restrict__ web, const float* __restrict__ bE,
    __hip_bfloat16* __restrict__ eout)
{
    __shared__ ushort Asb[EB][EPAD];
    __shared__ ushort Bsb[EB][EPAD];
    const int tid = threadIdx.x;
    const int w = tid >> 6, l = tid & 63;
    const int wm = w >> 1, wn = w & 1;
    const int sBase = blockIdx.y * EB;
    const int jBase = blockIdx.x * EB;

    f32x4 acc[4][4] = {};

    for (int kt = 0; kt < KF; kt += BK) {
        __syncthreads();
        #pragma unroll
        for (int it = 0; it < 4; ++it) {
            int idx = tid + it * 256;
            int row = idx >> 3, c4o = (idx & 7) << 2;
            ushort4 hv;
            if (kt < KU) {
                hv = *(const ushort4*)&uhi[(size_t)(sBase + row) * KU + kt + c4o];
            } else {
                float4 v = *(const float4*)&R32[kt - KU + c4o];
                hv.x = f2bf(v.x); hv.y = f2bf(v.y); hv.z = f2bf(v.z); hv.w = f2bf(v.w);
            }
            *(ushort4*)&Asb[row][c4o] = hv;
        }
        #pragma unroll
        for (int it = 0; it < 4; ++it) {
            int idx = tid + it * 256;
            int col = idx >> 3, c4o = (idx & 7) << 2;
            *(ushort4*)&Bsb[col][c4o] =
                *(const ushort4*)&web[(size_t)(jBase + col) * KF + kt + c4o];
        }
        __syncthreads();
        const int kq = (l >> 4) << 3;
        bf16x8 af[4], bff[4];
        #pragma unroll
        for (int i = 0; i < 4; ++i)
            af[i] = *(const bf16x8*)&Asb[wm * 64 + i * 16 + (l & 15)][kq];
        #pragma unroll
        for (int n = 0; n < 4; ++n)
            bff[n] = *(const bf16x8*)&Bsb[wn * 64 + n * 16 + (l & 15)][kq];
        #pragma unroll
        for (int i = 0; i < 4; ++i)
            #pragma unroll
            for (int n = 0; n < 4; ++n)
                acc[i][n] = __builtin_amdgcn_mfma_f32_16x16x32_bf16(af[i], bff[n], acc[i][n], 0, 0, 0);
    }
    #pragma unroll
    for (int i = 0; i < 4; ++i) {
        int row = sBase + wm * 64 + i * 16 + ((l >> 4) << 2);
        #pragma unroll
        for (int n = 0; n < 4; ++n) {
            int col = jBase + wn * 64 + n * 16 + (l & 15);
            float bb = bE[col];
            #pragma unroll
            for (int r = 0; r < 4; ++r)
                eout[(size_t)(row + r) * NJ + col] = __float2bfloat16(acc[i][n][r] + bb);
        }
    }
}

// ---- m-path: split-bf16 MFMA + fused gate; flags go to worklist ----
#define MP 40
union MSm {
    struct {
        ushort u1[128][MP], u2[128][MP];
        ushort w1[2][64][MP], w2[2][64][MP];
    } st;
    struct { float m[128][64]; } ep;
};

__global__ __launch_bounds__(256, 2) void k_m(
    const ushort* __restrict__ uhi, const ushort* __restrict__ ulo,
    const float* __restrict__ noise,
    const float* __restrict__ Wnn, const float* __restrict__ Wno,
    const float* __restrict__ Bc, const __hip_bfloat16* __restrict__ ews,
    int* __restrict__ cnt, int* __restrict__ wl, float* __restrict__ out)
{
    __shared__ MSm sm;
    const int tid = threadIdx.x;
    const int w = tid >> 6, l = tid & 63;
    const int wm = w >> 1, wn = w & 1;
    const int lr = l & 15;
    const int sBase = blockIdx.y * 128;
    const int jBase = blockIdx.x * 64;
    const int dBase = jBase >> 4;

    f32x4 acc1[4][2] = {}; f32x4 acc2[4][2] = {};

    for (int kt = 0; kt < KU; kt += BK) {
        __syncthreads();
        #pragma unroll
        for (int it = 0; it < 4; ++it) {
            int idx = tid + it * 256;
            int row = idx >> 3, c4o = (idx & 7) << 2;
            size_t off = (size_t)(sBase + row) * KU + kt + c4o;
            *(ushort4*)&sm.st.u1[row][c4o] = *(const ushort4*)&uhi[off];
            *(ushort4*)&sm.st.u2[row][c4o] = *(const ushort4*)&ulo[off];
        }
        #pragma unroll
        for (int it = 0; it < 4; ++it) {
            int idx = tid + it * 256;
            int mat = idx >> 9, col = (idx >> 3) & 63, c4o = (idx & 7) << 2;
            const float* W = mat ? Wno : Wnn;
            float4 v = *(const float4*)&W[(size_t)(jBase + col) * KF + kt + c4o];
            ushort4 hA, hB;
            hA.x = f2bf(v.x); hB.x = f2bf(v.x - bf2f(hA.x));
            hA.y = f2bf(v.y); hB.y = f2bf(v.y - bf2f(hA.y));
            hA.z = f2bf(v.z); hB.z = f2bf(v.z - bf2f(hA.z));
            hA.w = f2bf(v.w); hB.w = f2bf(v.w - bf2f(hA.w));
            *(ushort4*)&sm.st.w1[mat][col][c4o] = hA;
            *(ushort4*)&sm.st.w2[mat][col][c4o] = hB;
        }
        __syncthreads();
        const int kq = (l >> 4) << 3;
        bf16x8 a1[4], a2[4], p1[2][2], p2[2][2];
        #pragma unroll
        for (int i = 0; i < 4; ++i) {
            a1[i] = *(const bf16x8*)&sm.st.u1[wm * 64 + i * 16 + lr][kq];
            a2[i] = *(const bf16x8*)&sm.st.u2[wm * 64 + i * 16 + lr][kq];
        }
        #pragma unroll
        for (int mt = 0; mt < 2; ++mt)
            #pragma unroll
            for (int n = 0; n < 2; ++n) {
                p1[mt][n] = *(const bf16x8*)&sm.st.w1[mt][wn * 32 + n * 16 + lr][kq];
                p2[mt][n] = *(const bf16x8*)&sm.st.w2[mt][wn * 32 + n * 16 + lr][kq];
            }
        #pragma unroll
        for (int i = 0; i < 4; ++i)
            #pragma unroll
            for (int n = 0; n < 2; ++n) {
                acc1[i][n] = __builtin_amdgcn_mfma_f32_16x16x32_bf16(a1[i], p1[0][n], acc1[i][n], 0, 0, 0);
                acc1[i][n] = __builtin_amdgcn_mfma_f32_16x16x32_bf16(a1[i], p2[0][n], acc1[i][n], 0, 0, 0);
                acc1[i][n] = __builtin_amdgcn_mfma_f32_16x16x32_bf16(a2[i], p1[0][n], acc1[i][n], 0, 0, 0);
                acc2[i][n] = __builtin_amdgcn_mfma_f32_16x16x32_bf16(a1[i], p1[1][n], acc2[i][n], 0, 0, 0);
                acc2[i][n] = __builtin_amdgcn_mfma_f32_16x16x32_bf16(a1[i], p2[1][n], acc2[i][n], 0, 0, 0);
                acc2[i][n] = __builtin_amdgcn_mfma_f32_16x16x32_bf16(a2[i], p1[1][n], acc2[i][n], 0, 0, 0);
            }
    }

    __syncthreads();
    float bc1[2], bc2[2];
    #pragma unroll
    for (int n = 0; n < 2; ++n) {
        int col = jBase + wn * 32 + n * 16 + lr;
        bc1[n] = Bc[col];
        bc2[n] = Bc[NJ + col];
    }
    #pragma unroll
    for (int i = 0; i < 4; ++i)
        #pragma unroll
        for (int n = 0; n < 2; ++n) {
            int colL = wn * 32 + n * 16 + lr;
            #pragma unroll
            for (int r = 0; r < 4; ++r) {
                int rowL = wm * 64 + i * 16 + ((l >> 4) << 2) + r;
                float m1 = acc1[i][n][r] + bc1[n];
                float m2 = acc2[i][n][r] + bc2[n];
                float nz = noise[(size_t)(sBase + rowL) * NJ + jBase + colL];
                sm.ep.m[rowL][colL] = fmaf(m2, nz, m1);
            }
        }
    __syncthreads();

    for (int site = tid; site < 512; site += 256) {
        int srow = site >> 2, dl = site & 3;
        const __hip_bfloat16* ep = &ews[(size_t)(sBase + srow) * NJ + jBase + dl * 16];
        float v1 = -INFINITY, v2 = -INFINITY, v3 = -INFINITY;
        float ev1 = 0.f, ev2 = 0.f;
        #pragma unroll
        for (int e = 0; e < 16; ++e) {
            float m = sm.ep.m[srow][dl * 16 + e];
            float ev = bf2f(*reinterpret_cast<const ushort*>(&ep[e]));
            if (m > v1)      { v3 = v2; v2 = v1; ev2 = ev1; v1 = m; ev1 = ev; }
            else if (m > v2) { v3 = v2; v2 = m; ev2 = ev; }
            else if (m > v3) { v3 = m; }
        }
        int gidx = (sBase + srow) * DIMD + dBase + dl;
        bool flg = (v2 - v3 < GAP_T) || (fabsf(v1) < GAP_T) || (fabsf(v2) < GAP_T);
        if (flg) {
            int pos = atomicAdd(cnt, 1);
            wl[pos] = gidx;
        }
        double x1 = (double)v1, x2 = (double)v2;
        double vmax = fmax(x1, x2);
        double g1 = exp(x1 - vmax), g2 = exp(x2 - vmax);
        double num = g1 * (double)ev1 + g2 * (double)ev2;
        out[gidx] = (float)(num / (g1 + g2) * 0.0625);
    }
}

// ---- repair: one half-wave per flagged site; lane = (expert, mat) chain ----
__global__ __launch_bounds__(256) void k_repair(
    const float* __restrict__ u, const float* __restrict__ noise,
    const float* __restrict__ Wnn, const float* __restrict__ Wno,
    const float* __restrict__ bnn, const float* __restrict__ bno,
    const float* __restrict__ R32, const float* __restrict__ c4ws,
    const __hip_bfloat16* __restrict__ ews,
    const int* __restrict__ cnt, const int* __restrict__ wl,
    float* __restrict__ out)
{
    const int lane = threadIdx.x & 63;
    const int half = lane >> 5;
    const int sub = lane & 31;
    const int e = sub & 15, mt = sub >> 4;
    const int wid = (blockIdx.x * 256 + threadIdx.x) >> 6;
    const int hw = wid * 2 + half;
    const int NHW = (256 * 256 / 64) * 2;    // 2048 half-waves
    const int n = *cnt;

    for (int i = hw; i < n; i += NHW) {
        int si = wl[i];
        int s = si >> 9, d = si & 511;
        int j = d * 16 + e;
        const float* Wrow = (mt ? Wno : Wnn) + (size_t)j * KF;
        const float* urow = u + (size_t)s * KU;
        // exact KC-chunked f32 chain (identical order to reference emulation)
        float t = 0.f;
        #pragma unroll
        for (int c = 0; c < 3; ++c) {
            float cc = 0.f;
            int k0 = c * KC;
            for (int k = k0; k < k0 + KC; ++k) {
                float a = (k < KU) ? urow[k] : R32[k - KU];
                cc = fmaf(a, Wrow[k], cc);
            }
            t = __fadd_rn(t, cc);
        }
        t = __fadd_rn(t, c4ws[mt * NJ + j]);
        float hb = __fadd_rn(t, (mt ? bno[j] : bnn[j]));
        // combine h1 (mt=0 lanes) with partner h2 (mt=1 lanes)
        int src = (half << 5) | 16 | e;
        float h2 = __shfl(hb, src);
        float m = -INFINITY, ev = 0.f;
        if (mt == 0) {
            float nz = noise[(size_t)s * NJ + j];
            m = __fadd_rn(hb, __fmul_rn(h2, nz));
            ev = bf2f(*reinterpret_cast<const ushort*>(&ews[(size_t)s * NJ + j]));
        }
        // top-1 (index-stable) over 16-lane group
        float v1 = m; int i1 = e;
        #pragma unroll
        for (int mk = 1; mk <= 8; mk <<= 1) {
            float ov = __shfl_xor(v1, mk);
            int oi = __shfl_xor(i1, mk);
            if (ov > v1 || (ov == v1 && oi < i1)) { v1 = ov; i1 = oi; }
        }
        // top-2: exclude i1
        float v2 = (mt == 0 && e == i1) ? -INFINITY : m;
        int i2 = (mt == 0 && e == i1) ? 64 : e;
        #pragma unroll
        for (int mk = 1; mk <= 8; mk <<= 1) {
            float ov = __shfl_xor(v2, mk);
            int oi = __shfl_xor(i2, mk);
            if (ov > v2 || (ov == v2 && oi < i2)) { v2 = ov; i2 = oi; }
        }
        // sumE
        float se = ev;
        #pragma unroll
        for (int mk = 1; mk <= 8; mk <<= 1) se += __shfl_xor(se, mk);
        // fetch e-values of the selected experts
        float ev1 = __shfl(ev, (half << 5) + i1);
        float ev2 = __shfl(ev, (half << 5) + i2);
        if (sub == 0) {
            double x1 = (v1 == 0.0f) ? -100000.0 : (double)v1;
            double x2 = (v2 == 0.0f) ? -100000.0 : (double)v2;
            double vmax = fmax(fmax(x1, x2), -100000.0);
            double g1 = exp(x1 - vmax), g2 = exp(x2 - vmax), gz = exp(-100000.0 - vmax);
            double den = g1 + g2 + 14.0 * gz;
            double num = g1 * (double)ev1 + g2 * (double)ev2
                       + gz * ((double)se - (double)ev1 - (double)ev2);
            out[si] = (float)(num / den * 0.0625);
        }
    }
}

// ---- fallback: proven round-5 ws-free kernel (bit-identical arithmetic) ----
__global__ __launch_bounds__(256) void k_base(
    const float* __restrict__ u, const float* __restrict__ noise,
    const float* __restrict__ Wnn, const float* __restrict__ Wno, const float* __restrict__ WE,
    const float* __restrict__ bnn, const float* __restrict__ bno, const float* __restrict__ bE,
    const float* __restrict__ h, const float* __restrict__ us, const float* __restrict__ ue,
    const float* __restrict__ Wr, const float* __restrict__ br,
    float* __restrict__ out)
{
    __shared__ __align__(16) float As[BM][PA];
    __shared__ __align__(16) float Ws[3][BK][PW];
    __shared__ float Rsh[512];

    const int tid = threadIdx.x;
    const int sr = tid >> 2, dl = tid & 3;
    const int jBase = blockIdx.x * 64;
    const int sBase = blockIdx.y * BM;
    const int myCol = dl * 16;

    for (int o = tid; o < 512; o += 256) Rsh[o] = chainR(h, us, ue, Wr, br, o);

    float t1[16] = {}, c1[16] = {}, t2[16] = {}, c2[16] = {}, tE[16] = {}, cE[16] = {};

    for (int kt = 0; kt < KF; kt += BK) {
        __syncthreads();
        if (kt < KU) {
            for (int idx = tid; idx < BM * BK; idx += 256) {
                int r = idx >> 5, c = idx & 31;
                As[r][c] = u[(size_t)(sBase + r) * KU + kt + c];
            }
        }
        for (int idx = tid; idx < 64 * BK; idx += 256) {
            int col = idx >> 5, kk = idx & 31;
            size_t off = (size_t)(jBase + col) * KF + kt + kk;
            Ws[0][kk][col] = Wnn[off];
            Ws[1][kk][col] = Wno[off];
            Ws[2][kk][col] = WE[off];
        }
        __syncthreads();
        const bool uReg = (kt < KU);
        for (int kk = 0; kk < BK; ++kk) {
            float a = uReg ? As[sr][kk] : Rsh[kt + kk - KU];
            #pragma unroll
            for (int q = 0; q < 4; ++q) {
                float4 w0 = *(const float4*)&Ws[0][kk][myCol + 4 * q];
                float4 w1 = *(const float4*)&Ws[1][kk][myCol + 4 * q];
                float4 w2 = *(const float4*)&Ws[2][kk][myCol + 4 * q];
                c1[4*q+0] = fmaf(a, w0.x, c1[4*q+0]);
                c1[4*q+1] = fmaf(a, w0.y, c1[4*q+1]);
                c1[4*q+2] = fmaf(a, w0.z, c1[4*q+2]);
                c1[4*q+3] = fmaf(a, w0.w, c1[4*q+3]);
                c2[4*q+0] = fmaf(a, w1.x, c2[4*q+0]);
                c2[4*q+1] = fmaf(a, w1.y, c2[4*q+1]);
                c2[4*q+2] = fmaf(a, w1.z, c2[4*q+2]);
                c2[4*q+3] = fmaf(a, w1.w, c2[4*q+3]);
                cE[4*q+0] = fmaf(a, w2.x, cE[4*q+0]);
                cE[4*q+1] = fmaf(a, w2.y, cE[4*q+1]);
                cE[4*q+2] = fmaf(a, w2.z, cE[4*q+2]);
                cE[4*q+3] = fmaf(a, w2.w, cE[4*q+3]);
            }
        }
        if (((kt + BK) % KC) == 0 || (kt + BK) == KF) {
            #pragma unroll
            for (int e = 0; e < 16; ++e) {
                t1[e] = __fadd_rn(t1[e], c1[e]); c1[e] = 0.f;
                t2[e] = __fadd_rn(t2[e], c2[e]); c2[e] = 0.f;
                tE[e] = __fadd_rn(tE[e], cE[e]); cE[e] = 0.f;
            }
        }
    }

    const int s = sBase + sr;
    const int jb = jBase + myCol;
    float m32[16]; double evv[16];
    #pragma unroll
    for (int e = 0; e < 16; ++e) {
        float h1 = __fadd_rn(t1[e], bnn[jb + e]);
        float h2 = __fadd_rn(t2[e], bno[jb + e]);
        float nz = noise[(size_t)s * NJ + jb + e];
        m32[e] = __fadd_rn(h1, __fmul_rn(h2, nz));
        evv[e] = (double)__fadd_rn(tE[e], bE[jb + e]);
    }
    int i1 = 0; float v1 = m32[0];
    #pragma unroll
    for (int e = 1; e < 16; ++e) if (m32[e] > v1) { v1 = m32[e]; i1 = e; }
    int i2 = -1; float v2 = -INFINITY;
    #pragma unroll
    for (int e = 0; e < 16; ++e) if (e != i1 && m32[e] > v2) { v2 = m32[e]; i2 = e; }
    double e1 = 0.0, e2 = 0.0, sumE = 0.0;
    #pragma unroll
    for (int e = 0; e < 16; ++e) {
        e1 = (e == i1) ? evv[e] : e1;
        e2 = (e == i2) ? evv[e] : e2;
        sumE += evv[e];
    }
    double x1 = (v1 == 0.0f) ? -100000.0 : (double)v1;
    double x2 = (v2 == 0.0f) ? -100000.0 : (double)v2;
    double vmax = fmax(fmax(x1, x2), -100000.0);
    double g1 = exp(x1 - vmax), g2 = exp(x2 - vmax), gz = exp(-100000.0 - vmax);
    double den = g1 + g2 + 14.0 * gz;
    double num = g1 * e1 + g2 * e2 + gz * (sumE - e1 - e2);
    out[(size_t)s * DIMD + (jBase >> 4) + dl] = (float)(num / den * 0.0625);
}

extern "C" void kernel_launch(void* const* d_in, const int* in_sizes, int n_in,
                              void* d_out, int out_size, void* d_ws, size_t ws_size,
                              hipStream_t stream) {
    (void)in_sizes; (void)n_in; (void)out_size;
    const float* h     = (const float*)d_in[0];
    const float* us    = (const float*)d_in[1];
    const float* ue    = (const float*)d_in[2];
    const float* u     = (const float*)d_in[3];
    const float* noise = (const float*)d_in[4];
    const float* Wnn   = (const float*)d_in[5];
    const float* bnn   = (const float*)d_in[6];
    const float* Wno   = (const float*)d_in[7];
    const float* bno   = (const float*)d_in[8];
    const float* WE    = (const float*)d_in[9];
    const float* bE    = (const float*)d_in[10];
    const float* Wr    = (const float*)d_in[11];
    const float* br    = (const float*)d_in[12];
    float* out = (float*)d_out;

    if (ws_size >= WS_NEEDED) {
        char* ws = (char*)d_ws;
        float* Rws  = (float*)(ws + WS_R);
        float* c4ws = (float*)(ws + WS_C4);
        float* Bc   = (float*)(ws + WS_BC);
        int*   cnt  = (int*)(ws + WS_CNT);
        int*   wl   = (int*)(ws + WS_WL);
        ushort* uhi = (ushort*)(ws + WS_UHI);
        ushort* ulo = (ushort*)(ws + WS_ULO);
        ushort* web = (ushort*)(ws + WS_WEB);
        __hip_bfloat16* ews = (__hip_bfloat16*)(ws + WS_E);

        hipLaunchKernelGGL(k_R32, dim3(2), dim3(256), 0, stream, h, us, ue, Wr, br, Rws);
        hipLaunchKernelGGL(k_prep_u, dim3(SEQL * KU / 1024), dim3(256), 0, stream, u, uhi, ulo);
        hipLaunchKernelGGL(k_prep_we, dim3(NJ * KF / 1024), dim3(256), 0, stream, WE, web);
        hipLaunchKernelGGL(k_c4, dim3(64), dim3(256), 0, stream, Rws, Wnn, Wno, c4ws);
        hipLaunchKernelGGL(k_bc, dim3(64), dim3(256), 0, stream, Rws, Wnn, Wno, bnn, bno, Bc);
        hipLaunchKernelGGL(k_e, dim3(NJ / EB, SEQL / EB), dim3(256), 0, stream,
                           uhi, Rws, web, bE, ews);
        hipLaunchKernelGGL(k_zero, dim3(1), dim3(1), 0, stream, cnt);
        hipLaunchKernelGGL(k_m, dim3(NJ / 64, SEQL / 128), dim3(256), 0, stream,
                           uhi, ulo, noise, Wnn, Wno, Bc, ews, cnt, wl, out);
        hipLaunchKernelGGL(k_repair, dim3(256), dim3(256), 0, stream,
                           u, noise, Wnn, Wno, bnn, bno, Rws, c4ws, ews, cnt, wl, out);
    } else {
        hipLaunchKernelGGL(k_base, dim3(NJ / 64, SEQL / BM), dim3(256), 0, stream,
                           u, noise, Wnn, Wno, WE, bnn, bno, bE,
                           h, us, ue, Wr, br, out);
    }
}